// Round 1
// baseline (285.845 us; speedup 1.0000x reference)
//
#include <hip/hip_runtime.h>
#include <string.h>

#define D_ 128
#define P_ 3600
#define N_ 57600
#define C_ 19
#define NB 2
#define NSPLIT 30
#define CPB 15       // 450 chunks of 128 cols / NSPLIT
#define PT 29        // ceil(3600/128)

typedef short bf16x8 __attribute__((ext_vector_type(8)));
typedef float f32x4 __attribute__((ext_vector_type(4)));

__device__ __forceinline__ ushort f2bf(float x) {
  unsigned u = __float_as_uint(x);
  u = (u + 0x7fffu + ((u >> 16) & 1u)) >> 16;   // RNE to bf16
  return (ushort)u;
}

// ---- prep: [D,M] fp32 -> [M,128] bf16 (optionally pre-scaled) ----
__global__ void transpose_cvt_kernel(const float* __restrict__ X, ushort* __restrict__ Y,
                                     int M, float scale) {
  __shared__ float T[64][129];
  const int b = blockIdx.y;
  const int nbase = blockIdx.x * 64;
  const float* Xb = X + (size_t)b * D_ * M;
  ushort* Yb = Y + (size_t)b * M * D_;
  const int tid = threadIdx.x;
  const int nl = tid & 63;
  const int dw = tid >> 6;
#pragma unroll
  for (int i = 0; i < 32; ++i) {
    int d = i * 4 + dw;
    int gn = nbase + nl; if (gn >= M) gn = M - 1;
    T[nl][d] = Xb[(size_t)d * M + gn];
  }
  __syncthreads();
  const int d0 = (tid & 31) * 4;
#pragma unroll
  for (int i = 0; i < 8; ++i) {
    int n = i * 8 + (tid >> 5);
    int gn = nbase + n;
    if (gn < M) {
      ushort4 u;
      u.x = f2bf(T[n][d0 + 0] * scale);
      u.y = f2bf(T[n][d0 + 1] * scale);
      u.z = f2bf(T[n][d0 + 2] * scale);
      u.w = f2bf(T[n][d0 + 3] * scale);
      *(ushort4*)(Yb + (size_t)gn * D_ + d0) = u;
    }
  }
}

// ---- prep: argmax over C for negatives ----
__global__ void neg_labels_kernel(const float* __restrict__ npl, int* __restrict__ nlab) {
  int b = blockIdx.y;
  int n = blockIdx.x * 256 + threadIdx.x;
  const float* base = npl + (size_t)b * C_ * N_ + n;
  float best = base[0]; int bi = 0;
#pragma unroll
  for (int c = 1; c < C_; ++c) {
    float v = base[(size_t)c * N_];
    if (v > best) { best = v; bi = c; }
  }
  nlab[b * N_ + n] = bi;
}

// ---- prep: labels1, mask1 (argmax of 0/1 combo = first true else 0), pos1 ----
__global__ void anchor_kernel(const float* __restrict__ pl1, const float* __restrict__ pl2,
                              const float* __restrict__ f1, const float* __restrict__ f2,
                              int* __restrict__ lab1, float* __restrict__ mask1,
                              float* __restrict__ pos1) {
  int b = blockIdx.y;
  int p = blockIdx.x * 256 + threadIdx.x;
  if (p >= P_) return;
  const float* a1 = pl1 + (size_t)b * C_ * P_ + p;
  const float* a2 = pl2 + (size_t)b * C_ * P_ + p;
  float best = a1[0]; int bi = 0;
  int mfirst = ((a1[0] < a2[0]) && (a2[0] > 0.75f)) ? 0 : -1;
#pragma unroll
  for (int c = 1; c < C_; ++c) {
    float v1 = a1[(size_t)c * P_], v2 = a2[(size_t)c * P_];
    if (v1 > best) { best = v1; bi = c; }
    if (mfirst < 0 && (v1 < v2) && (v2 > 0.75f)) mfirst = c;
  }
  lab1[b * P_ + p] = bi;
  mask1[b * P_ + p] = (mfirst < 0) ? 0.0f : (float)mfirst;
  const float* g1 = f1 + (size_t)b * D_ * P_ + p;
  const float* g2 = f2 + (size_t)b * D_ * P_ + p;
  float s = 0.f;
#pragma unroll 8
  for (int d = 0; d < D_; ++d) s += g1[(size_t)d * P_] * g2[(size_t)d * P_];
  pos1[b * P_ + p] = s * 10.0f;   // /TEMP
}

// ---- fused GEMM + exp + mask + row-sum ----
// grid (PT, NSPLIT, NB), block 256. LDS: 2 x 128x128 bf16 (XOR-swizzled) = 64 KiB.
__global__ __launch_bounds__(256, 2) void gemm_kernel(
    const ushort* __restrict__ At, const ushort* __restrict__ Bt,
    const int* __restrict__ lab1g, const int* __restrict__ nlabg,
    float* __restrict__ neg_logits) {
  __shared__ __attribute__((aligned(16))) ushort As[128 * 128];
  __shared__ __attribute__((aligned(16))) ushort Bs[128 * 128];
  const int tid = threadIdx.x;
  const int b = blockIdx.z;
  const int ptile = blockIdx.x;
  const int wid = tid >> 6, lane = tid & 63;
  const int quad = lane >> 4, lm = lane & 15;
  const int qr = wid & 1, qc = wid >> 1;
  const ushort* Atb = At + (size_t)b * P_ * D_;
  const ushort* Btb = Bt + (size_t)b * N_ * D_;
  const int* lab1 = lab1g + b * P_;
  const int* nlab = nlabg + b * N_;

  // stage A tile once (rows clamped for the partial last tile)
#pragma unroll
  for (int i = 0; i < 8; ++i) {
    int cid = tid + i * 256;
    int row = cid >> 4, cc = cid & 15;
    int p = ptile * 128 + row; if (p > P_ - 1) p = P_ - 1;
    uint4 v = *(const uint4*)(Atb + (size_t)p * D_ + cc * 8);
    *(uint4*)(&As[row * 128 + (cc ^ (row & 7)) * 8]) = v;
  }
  __syncthreads();

  // hold all 16 A fragments in registers for the whole block
  bf16x8 af[4][4];
#pragma unroll
  for (int r = 0; r < 4; ++r) {
    int row = qr * 64 + r * 16 + lm;
#pragma unroll
    for (int k0 = 0; k0 < 4; ++k0) {
      int ch = (k0 * 4 + quad) ^ (row & 7);
      af[r][k0] = *(const bf16x8*)(&As[row * 128 + ch * 8]);
    }
  }

  // labels of my 16 output rows
  int labp[16];
#pragma unroll
  for (int r = 0; r < 4; ++r)
#pragma unroll
    for (int g = 0; g < 4; ++g) {
      int p = ptile * 128 + qr * 64 + r * 16 + quad * 4 + g;
      labp[r * 4 + g] = lab1[p > P_ - 1 ? P_ - 1 : p];
    }

  float rsum[16];
#pragma unroll
  for (int i = 0; i < 16; ++i) rsum[i] = 0.f;

  for (int j = 0; j < CPB; ++j) {
    const int nbase = (blockIdx.y * CPB + j) * 128;
    __syncthreads();
#pragma unroll
    for (int i = 0; i < 8; ++i) {
      int cid = tid + i * 256;
      int row = cid >> 4, cc = cid & 15;
      uint4 v = *(const uint4*)(Btb + (size_t)(nbase + row) * D_ + cc * 8);
      *(uint4*)(&Bs[row * 128 + (cc ^ (row & 7)) * 8]) = v;
    }
    __syncthreads();

    f32x4 acc[4][4];
#pragma unroll
    for (int r = 0; r < 4; ++r)
#pragma unroll
      for (int c = 0; c < 4; ++c)
#pragma unroll
        for (int g = 0; g < 4; ++g) acc[r][c][g] = 0.f;

#pragma unroll
    for (int c = 0; c < 4; ++c) {
      int row = qc * 64 + c * 16 + lm;
#pragma unroll
      for (int k0 = 0; k0 < 4; ++k0) {
        int ch = (k0 * 4 + quad) ^ (row & 7);
        bf16x8 bf = *(const bf16x8*)(&Bs[row * 128 + ch * 8]);
#pragma unroll
        for (int r = 0; r < 4; ++r)
          acc[r][c] = __builtin_amdgcn_mfma_f32_16x16x32_bf16(af[r][k0], bf, acc[r][c], 0, 0, 0);
      }
    }

    // epilogue: exp + label mask + accumulate per-lane row sums
#pragma unroll
    for (int c = 0; c < 4; ++c) {
      int nl = nlab[nbase + qc * 64 + c * 16 + lm];
#pragma unroll
      for (int r = 0; r < 4; ++r)
#pragma unroll
        for (int g = 0; g < 4; ++g) {
          float e = __expf(acc[r][c][g]);   // acc is already score/TEMP (A pre-scaled)
          rsum[r * 4 + g] += (labp[r * 4 + g] != nl) ? e : 0.f;
        }
    }
  }

  // reduce over the 16 lanes sharing a column group
#pragma unroll
  for (int i = 0; i < 16; ++i) {
    float v = rsum[i];
    v += __shfl_xor(v, 1);
    v += __shfl_xor(v, 2);
    v += __shfl_xor(v, 4);
    v += __shfl_xor(v, 8);
    rsum[i] = v;
  }
  if (lm == 0) {
#pragma unroll
    for (int r = 0; r < 4; ++r)
#pragma unroll
      for (int g = 0; g < 4; ++g) {
        int p = ptile * 128 + qr * 64 + r * 16 + quad * 4 + g;
        if (p < P_) atomicAdd(&neg_logits[b * P_ + p], rsum[r * 4 + g]);
      }
  }
}

// ---- finalize: weighted means, scalar out ----
__global__ void finalize_kernel(const float* __restrict__ neg_logits,
                                const float* __restrict__ pos1,
                                const float* __restrict__ mask1,
                                float* __restrict__ out) {
  double s1[2] = {0.0, 0.0}, s2[2] = {0.0, 0.0};
  for (int idx = threadIdx.x; idx < NB * P_; idx += 256) {
    int b = idx / P_;
    float ne = neg_logits[idx];
    float pe = __expf(pos1[idx]);
    float l = -logf(pe / (pe + ne + 1e-8f) + 1e-8f);
    float w = mask1[idx];
    s1[b] += (double)(w * l);
    s2[b] += (double)w;
  }
#pragma unroll
  for (int off = 32; off > 0; off >>= 1) {
    s1[0] += __shfl_down(s1[0], off);
    s2[0] += __shfl_down(s2[0], off);
    s1[1] += __shfl_down(s1[1], off);
    s2[1] += __shfl_down(s2[1], off);
  }
  __shared__ double sm[4][4];
  int wid = threadIdx.x >> 6, lane = threadIdx.x & 63;
  if (lane == 0) { sm[wid][0] = s1[0]; sm[wid][1] = s2[0]; sm[wid][2] = s1[1]; sm[wid][3] = s2[1]; }
  __syncthreads();
  if (threadIdx.x == 0) {
    double a = 0, bsum = 0, c = 0, d = 0;
    for (int w = 0; w < 4; ++w) { a += sm[w][0]; bsum += sm[w][1]; c += sm[w][2]; d += sm[w][3]; }
    out[0] = (float)(0.1 * (a / (bsum + 1e-8) + c / (d + 1e-8)));
  }
}

extern "C" void kernel_launch(void* const* d_in, const int* in_sizes, int n_in,
                              void* d_out, int out_size, void* d_ws, size_t ws_size,
                              hipStream_t stream) {
  const float* feats_view1 = (const float*)d_in[0];
  const float* pos_feats1  = (const float*)d_in[1];
  const float* pos_feats2  = (const float*)d_in[2];
  const float* pl1 = (const float*)d_in[3];
  const float* pl2 = (const float*)d_in[4];
  const float* npl = (const float*)d_in[5];

  char* ws = (char*)d_ws;
  ushort* Bt        = (ushort*)(ws + 0);          // 2*57600*128*2 = 29,491,200
  ushort* At        = (ushort*)(ws + 29491200);   //  1,843,200
  int*    nlab      = (int*)   (ws + 31334400);   //    460,800
  int*    lab1      = (int*)   (ws + 31795200);   //     28,800
  float*  mask1     = (float*) (ws + 31824000);   //     28,800
  float*  pos1      = (float*) (ws + 31852800);   //     28,800
  float*  neg_logits= (float*) (ws + 31881600);   //     28,800

  hipMemsetAsync(neg_logits, 0, NB * P_ * sizeof(float), stream);

  transpose_cvt_kernel<<<dim3(N_ / 64, NB), 256, 0, stream>>>(feats_view1, Bt, N_, 1.0f);
  transpose_cvt_kernel<<<dim3((P_ + 63) / 64, NB), 256, 0, stream>>>(pos_feats1, At, P_, 10.0f);
  neg_labels_kernel<<<dim3(N_ / 256, NB), 256, 0, stream>>>(npl, nlab);
  anchor_kernel<<<dim3((P_ + 255) / 256, NB), 256, 0, stream>>>(pl1, pl2, pos_feats1, pos_feats2,
                                                                lab1, mask1, pos1);
  gemm_kernel<<<dim3(PT, NSPLIT, NB), 256, 0, stream>>>(At, Bt, lab1, nlab, neg_logits);
  finalize_kernel<<<1, 256, 0, stream>>>(neg_logits, pos1, mask1, (float*)d_out);
}